// Round 10
// baseline (4398.285 us; speedup 1.0000x reference)
//
#include <hip/hip_runtime.h>
#include <cmath>

// Problem constants (fixed by reference)
#define SS 3
#define NN 8192
#define EE 1024
#define DD 512
#define ALPHA 3.0f
// z-margin below which a row is recomputed in exact fp32.
// 2-term split (ah*bh + ah*bl): dropped term al*b gives sigma_z ~= 0.08
// (3*sqrt(512)*2^-9/sqrt(3)), row-norm scaled <=~0.09. TAU=0.7 ~= 8 sigma.
// Expected flag rate ~1% (~250 rows of 24576); exact fixup handles them.
#define TAU 0.7f

typedef __attribute__((ext_vector_type(8))) short bf16x8;
typedef __attribute__((ext_vector_type(4))) float f32x4;

#define AS1(p) ((const __attribute__((address_space(1))) void*)(p))
#define AS3(p) ((__attribute__((address_space(3))) void*)(p))

// ---------------- helpers ----------------
__device__ __forceinline__ unsigned short f2bf(float x) {
    unsigned u = __float_as_uint(x);
    return (unsigned short)((u + 0x7fffu + ((u >> 16) & 1u)) >> 16);
}
__device__ __forceinline__ float bf2f(unsigned short h) {
    return __uint_as_float(((unsigned)h) << 16);
}

__device__ __forceinline__ void gload_lds16(const unsigned short* g, unsigned short* l) {
    __builtin_amdgcn_global_load_lds(AS1(g), AS3(l), 16, 0, 0);
}

// ---------------- kernel A: split. A -> hi only; B -> (hi, lo) ----------------
__global__ __launch_bounds__(256)
void split_both_kernel(const float* __restrict__ node, const float* __restrict__ edge,
                       unsigned short* __restrict__ Ah,
                       unsigned short* __restrict__ Bh, unsigned short* __restrict__ Bl)
{
    const int nA = SS * NN * DD / 4;
    const int nB = SS * EE * DD / 4;
    int i = blockIdx.x * blockDim.x + threadIdx.x;

    if (i < nA) {
        float4 v = ((const float4*)node)[i];
        ushort4 h;
        h.x = f2bf(v.x); h.y = f2bf(v.y); h.z = f2bf(v.z); h.w = f2bf(v.w);
        ((ushort4*)Ah)[i] = h;
    } else if (i < nA + nB) {
        int idx = i - nA;
        float4 v = ((const float4*)edge)[idx];
        ushort4 h, l;
        h.x = f2bf(v.x); l.x = f2bf(v.x - bf2f(h.x));
        h.y = f2bf(v.y); l.y = f2bf(v.y - bf2f(h.y));
        h.z = f2bf(v.z); l.z = f2bf(v.z - bf2f(h.z));
        h.w = f2bf(v.w); l.w = f2bf(v.w - bf2f(h.w));
        ((ushort4*)Bh)[idx] = h;
        ((ushort4*)Bl)[idx] = l;
    }
}

// ---------------- kernel B: 2-term split-bf16 MFMA GEMM, z = relu(alpha*sim) --------
// Round-5 verified structure: 128x128 tile, BK=32, 4 waves, 2-barrier K-loop,
// m-fastest grid (XCD A-panel L2 locality), 16x16x32 MFMA, coalesced staging
// with XOR chunk swizzle. 2 terms per frag position: ah*bh + ah*bl (= ah*b
// to 2^-17; dropped al*b covered by TAU+fixup). A-lo plane eliminated.
//
// LDS 24KB/step: A region rows 0..127 x 4 slots x 16B (slot = j ^ ((row>>1)&3):
// bank class = (row&1)*16 + slot*4 -> 8 classes, 2 lanes each on frag reads,
// conflict-free). B region at 4096 ushorts: rows 0..127 x 8 slots x 16B
// (slot = j ^ (row&7), byte-identical pattern to round 5, verified 0 conflicts).
// Per wave-K-step: 12 ds_read_b128 + 32 MFMA.
__global__ __launch_bounds__(256)
void gemm_mfma_kernel(const unsigned short* __restrict__ Ah,
                      const unsigned short* __restrict__ Bh,
                      const unsigned short* __restrict__ Bl,
                      float* __restrict__ out)
{
    const int s  = blockIdx.z;
    const int m0 = blockIdx.x * 128;   // m-fastest for XCD A-panel locality
    const int n0 = blockIdx.y * 128;

    const unsigned short* pAh = Ah + (size_t)s * NN * DD;
    const unsigned short* pBh = Bh + (size_t)s * EE * DD;
    const unsigned short* pBl = Bl + (size_t)s * EE * DD;
    float* C = out + (size_t)s * NN * EE;

    // A: 128*4*8 = 4096 ushorts; B: 128*8*8 = 8192 ushorts; total 24KB
    __shared__ unsigned short lds[12288];

    const int t    = threadIdx.x;
    const int lane = t & 63;
    const int wid  = t >> 6;
    const int wm   = wid >> 1;       // wave row (0..1), 64 rows
    const int wn   = wid & 1;        // wave col (0..1), 64 cols
    const int fr   = lane & 15;      // row within 16x16 frag
    const int kg   = lane >> 4;      // k-group (0..3), 8 bf16 each

    f32x4 acc[4][4];
#pragma unroll
    for (int i = 0; i < 4; ++i)
#pragma unroll
        for (int j = 0; j < 4; ++j) acc[i][j] = (f32x4){0.f, 0.f, 0.f, 0.f};

    for (int k0 = 0; k0 < DD; k0 += 32) {
        // stage 1536 chunks of 16B (A-hi: 0..511, B: 512..1535), 6 per thread.
        // LDS dest linear in chunk id; global source picks chunk j via the
        // inverse slot swizzle (both-sides-or-neither).
#pragma unroll
        for (int i = 0; i < 6; ++i) {
            const int c = i * 256 + t;
            const unsigned short* src;
            if (c < 512) {
                const int row  = c >> 2;
                const int slot = c & 3;
                const int j    = slot ^ ((row >> 1) & 3);
                src = pAh + (size_t)(m0 + row) * DD + k0 + j * 8;
            } else {
                const int c2   = c - 512;
                const int row  = c2 >> 3;
                const int slot = c2 & 7;
                const int j    = slot ^ (row & 7);
                src = (j < 4) ? pBh + (size_t)(n0 + row) * DD + k0 + j * 8
                              : pBl + (size_t)(n0 + row) * DD + k0 + (j - 4) * 8;
            }
            gload_lds16(src, &lds[c * 8]);
        }
        __syncthreads();

        bf16x8 a[4], bh[4], bl[4];
#pragma unroll
        for (int i = 0; i < 4; ++i) {
            const int r = wm * 64 + i * 16 + fr;
            a[i] = *(const bf16x8*)&lds[r * 32 + (kg ^ ((r >> 1) & 3)) * 8];
        }
#pragma unroll
        for (int j = 0; j < 4; ++j) {
            const int r = wn * 64 + j * 16 + fr;
            bh[j] = *(const bf16x8*)&lds[4096 + r * 64 + ((kg)     ^ (r & 7)) * 8];
            bl[j] = *(const bf16x8*)&lds[4096 + r * 64 + ((4 + kg) ^ (r & 7)) * 8];
        }
#pragma unroll
        for (int i = 0; i < 4; ++i)
#pragma unroll
            for (int j = 0; j < 4; ++j) {
                acc[i][j] = __builtin_amdgcn_mfma_f32_16x16x32_bf16(a[i], bh[j], acc[i][j], 0, 0, 0);
                acc[i][j] = __builtin_amdgcn_mfma_f32_16x16x32_bf16(a[i], bl[j], acc[i][j], 0, 0, 0);
            }
        __syncthreads();
    }

    // epilogue: z = relu(alpha * acc); C/D layout: col=lane&15, row=(lane>>4)*4+reg
#pragma unroll
    for (int i = 0; i < 4; ++i)
#pragma unroll
        for (int j = 0; j < 4; ++j) {
            const int col = n0 + wn * 64 + j * 16 + fr;
#pragma unroll
            for (int r = 0; r < 4; ++r) {
                const int row = m0 + wm * 64 + i * 16 + kg * 4 + r;
                C[(size_t)row * EE + col] = fmaxf(ALPHA * acc[i][j][r], 0.f);
            }
        }
}

// ---------------- kernel Z: zero the worklist counter ----------------
__global__ void zero_count_kernel(int* __restrict__ count) {
    if (threadIdx.x == 0 && blockIdx.x == 0) count[0] = 0;
}

// ---------------- kernel C: softmax threshold + borderline worklist ----------------
__global__ __launch_bounds__(256)
void softmax_threshold_flag_kernel(float* __restrict__ out,
                                   int* __restrict__ count,
                                   int* __restrict__ worklist)
{
    const int wave = threadIdx.x >> 6;
    const int lane = threadIdx.x & 63;
    const size_t row = (size_t)blockIdx.x * 4 + wave;
    float* p = out + row * EE;

    float z[16];
    float m = 0.f;  // z >= 0 (relu output)
#pragma unroll
    for (int j = 0; j < 4; ++j) {
        float4 v = *(const float4*)(p + j * 256 + lane * 4);
        z[j*4+0] = v.x; z[j*4+1] = v.y; z[j*4+2] = v.z; z[j*4+3] = v.w;
        m = fmaxf(m, fmaxf(fmaxf(v.x, v.y), fmaxf(v.z, v.w)));
    }
#pragma unroll
    for (int off = 32; off >= 1; off >>= 1)
        m = fmaxf(m, __shfl_xor(m, off, 64));

    float e[16];
    float sum = 0.f;
#pragma unroll
    for (int j = 0; j < 16; ++j) {
        e[j] = expf(z[j] - m);
        sum += e[j];
    }
#pragma unroll
    for (int off = 32; off >= 1; off >>= 1)
        sum += __shfl_xor(sum, off, 64);

    const float thr = 0.5f * sum;
    const float T   = m + logf(thr);   // z-space threshold
    int lf = 0;
#pragma unroll
    for (int j = 0; j < 16; ++j)
        lf |= (fabsf(z[j] - T) < TAU) ? 1 : 0;

#pragma unroll
    for (int j = 0; j < 4; ++j) {
        float4 o;
        o.x = (e[j*4+0] > thr) ? 1.f : 0.f;
        o.y = (e[j*4+1] > thr) ? 1.f : 0.f;
        o.z = (e[j*4+2] > thr) ? 1.f : 0.f;
        o.w = (e[j*4+3] > thr) ? 1.f : 0.f;
        *(float4*)(p + j * 256 + lane * 4) = o;
    }
    const int anyf = __any(lf);
    if (anyf && lane == 0) {
        int idx = atomicAdd(count, 1);
        worklist[idx] = (int)row;
    }
}

// ---------------- kernel D1: parallel fp32 z-recompute of worklisted rows ----
__global__ __launch_bounds__(256)
void fixup_z_kernel(const float* __restrict__ node, const float* __restrict__ edge,
                    const int* __restrict__ count, const int* __restrict__ worklist,
                    float* __restrict__ zbuf, int zcap)
{
    __shared__ float sa[DD];
    const int t    = threadIdx.x;
    const int lane = t & 63;
    const int wid  = t >> 6;

    int nwork = count[0];
    if (nwork > zcap) nwork = zcap;
    const int items = nwork * 4;

    for (int item = blockIdx.x; item < items; item += gridDim.x) {
        const int w   = item >> 2;
        const int row = worklist[w];
        const int c0  = (item & 3) * 256;
        const int s   = row / NN;
        const float* a = node + (size_t)row * DD;
        const float* B = edge + (size_t)s * EE * DD;

        __syncthreads();   // protect sa from previous item
        if (t < DD / 4) ((float4*)sa)[t] = ((const float4*)a)[t];
        __syncthreads();

        const float4 va0 = ((const float4*)sa)[lane];
        const float4 va1 = ((const float4*)sa)[64 + lane];

        const int cbase = c0 + wid * 64;
        for (int g = 0; g < 16; ++g) {
            float acc[4];
#pragma unroll
            for (int j = 0; j < 4; ++j) {
                const float* b = B + (size_t)(cbase + g * 4 + j) * DD;
                float4 b0 = *(const float4*)(b + lane * 4);
                float4 b1 = *(const float4*)(b + 256 + lane * 4);
                float av;
                av = va0.x * b0.x;
                av = fmaf(va0.y, b0.y, av);
                av = fmaf(va0.z, b0.z, av);
                av = fmaf(va0.w, b0.w, av);
                av = fmaf(va1.x, b1.x, av);
                av = fmaf(va1.y, b1.y, av);
                av = fmaf(va1.z, b1.z, av);
                av = fmaf(va1.w, b1.w, av);
                acc[j] = av;
            }
#pragma unroll
            for (int off = 32; off >= 1; off >>= 1) {
#pragma unroll
                for (int j = 0; j < 4; ++j)
                    acc[j] += __shfl_xor(acc[j], off, 64);
            }
            if (lane == 0) {
#pragma unroll
                for (int j = 0; j < 4; ++j)
                    zbuf[(size_t)w * EE + cbase + g * 4 + j] = fmaxf(ALPHA * acc[j], 0.f);
            }
        }
    }
}

// ---------------- kernel D2: softmax+threshold of recomputed rows ----------
__global__ __launch_bounds__(256)
void fixup_finish_kernel(const float* __restrict__ zbuf,
                         const int* __restrict__ count, const int* __restrict__ worklist,
                         float* __restrict__ out, int zcap)
{
    const int lane = threadIdx.x & 63;
    const int wid  = threadIdx.x >> 6;
    int nwork = count[0];
    if (nwork > zcap) nwork = zcap;

    for (int w = blockIdx.x * 4 + wid; w < nwork; w += gridDim.x * 4) {
        const int row = worklist[w];
        const float* p = zbuf + (size_t)w * EE;

        float z[16];
        float m = 0.f;
#pragma unroll
        for (int j = 0; j < 4; ++j) {
            float4 v = *(const float4*)(p + j * 256 + lane * 4);
            z[j*4+0] = v.x; z[j*4+1] = v.y; z[j*4+2] = v.z; z[j*4+3] = v.w;
            m = fmaxf(m, fmaxf(fmaxf(v.x, v.y), fmaxf(v.z, v.w)));
        }
#pragma unroll
        for (int off = 32; off >= 1; off >>= 1)
            m = fmaxf(m, __shfl_xor(m, off, 64));

        float e[16], sum = 0.f;
#pragma unroll
        for (int j = 0; j < 16; ++j) { e[j] = expf(z[j] - m); sum += e[j]; }
#pragma unroll
        for (int off = 32; off >= 1; off >>= 1)
            sum += __shfl_xor(sum, off, 64);

        const float thr = 0.5f * sum;
        float* q = out + (size_t)row * EE;
#pragma unroll
        for (int j = 0; j < 4; ++j) {
            float4 o;
            o.x = (e[j*4+0] > thr) ? 1.f : 0.f;
            o.y = (e[j*4+1] > thr) ? 1.f : 0.f;
            o.z = (e[j*4+2] > thr) ? 1.f : 0.f;
            o.w = (e[j*4+3] > thr) ? 1.f : 0.f;
            *(float4*)(q + j * 256 + lane * 4) = o;
        }
    }
}

// ---------------- kernel D3: slow-path fixup for rows beyond zcap ----------
__global__ __launch_bounds__(256)
void fixup2_kernel(const float* __restrict__ node, const float* __restrict__ edge,
                   const int* __restrict__ count, const int* __restrict__ worklist,
                   float* __restrict__ out, int start)
{
    __shared__ float sa[DD];
    __shared__ float zrow[EE];
    __shared__ float red[8];

    const int t    = threadIdx.x;
    const int lane = t & 63;
    const int wid  = t >> 6;
    const int nwork = count[0];

    for (int w = start + blockIdx.x; w < nwork; w += gridDim.x) {
        const int row = worklist[w];
        const int s = row / NN;
        const float* a = node + (size_t)row * DD;
        const float* B = edge + (size_t)s * EE * DD;

        __syncthreads();
        if (t < DD / 4) ((float4*)sa)[t] = ((const float4*)a)[t];
        __syncthreads();

        float4 va0 = ((const float4*)sa)[lane];
        float4 va1 = ((const float4*)sa)[64 + lane];

        for (int c = wid; c < EE; c += 4) {
            const float* b = B + (size_t)c * DD;
            float4 b0 = *(const float4*)(b + lane * 4);
            float4 b1 = *(const float4*)(b + 256 + lane * 4);
            float acc;
            acc = va0.x * b0.x;
            acc = fmaf(va0.y, b0.y, acc);
            acc = fmaf(va0.z, b0.z, acc);
            acc = fmaf(va0.w, b0.w, acc);
            acc = fmaf(va1.x, b1.x, acc);
            acc = fmaf(va1.y, b1.y, acc);
            acc = fmaf(va1.z, b1.z, acc);
            acc = fmaf(va1.w, b1.w, acc);
#pragma unroll
            for (int off = 32; off >= 1; off >>= 1)
                acc += __shfl_xor(acc, off, 64);
            if (lane == 0) zrow[c] = fmaxf(ALPHA * acc, 0.f);
        }
        __syncthreads();

        float z[4], m = 0.f;
#pragma unroll
        for (int j = 0; j < 4; ++j) {
            z[j] = zrow[j * 256 + t];
            m = fmaxf(m, z[j]);
        }
#pragma unroll
        for (int off = 32; off >= 1; off >>= 1)
            m = fmaxf(m, __shfl_xor(m, off, 64));
        if (lane == 0) red[wid] = m;
        __syncthreads();
        m = fmaxf(fmaxf(red[0], red[1]), fmaxf(red[2], red[3]));

        float e[4], sum = 0.f;
#pragma unroll
        for (int j = 0; j < 4; ++j) { e[j] = expf(z[j] - m); sum += e[j]; }
#pragma unroll
        for (int off = 32; off >= 1; off >>= 1)
            sum += __shfl_xor(sum, off, 64);
        if (lane == 0) red[4 + wid] = sum;
        __syncthreads();
        sum = red[4] + red[5] + red[6] + red[7];

        const float thr = 0.5f * sum;
#pragma unroll
        for (int j = 0; j < 4; ++j)
            out[(size_t)row * EE + j * 256 + t] = (e[j] > thr) ? 1.f : 0.f;
        __syncthreads();
    }
}

// ---------------- fallback fp32 path (round-0, verified) ----------------
#define BM 128
#define BN 128
#define BK 16
#define TM 8
#define TN 8

__global__ __launch_bounds__(256, 2)
void gemm_relu_kernel(const float* __restrict__ node,
                      const float* __restrict__ edge,
                      float* __restrict__ out)
{
    const int s  = blockIdx.z;
    const int m0 = blockIdx.y * BM;
    const int n0 = blockIdx.x * BN;

    const float* A = node + (size_t)s * NN * DD;
    const float* B = edge + (size_t)s * EE * DD;
    float*       C = out  + (size_t)s * NN * EE;

    __shared__ float As[BK][BM + 4];
    __shared__ float Bs[BK][BN + 4];

    const int tid = threadIdx.x;
    const int tx  = tid % 16;
    const int ty  = tid / 16;
    const int lrow = tid / 4;
    const int lcol = (tid % 4) * 4;

    float acc[TM][TN];
#pragma unroll
    for (int i = 0; i < TM; ++i)
#pragma unroll
        for (int j = 0; j < TN; ++j) acc[i][j] = 0.f;

    for (int k0 = 0; k0 < DD; k0 += BK) {
#pragma unroll
        for (int p = 0; p < 2; ++p) {
            const int r = lrow + p * 64;
            float4 v = *(const float4*)(A + (size_t)(m0 + r) * DD + k0 + lcol);
            As[lcol + 0][r] = v.x; As[lcol + 1][r] = v.y;
            As[lcol + 2][r] = v.z; As[lcol + 3][r] = v.w;
            float4 w = *(const float4*)(B + (size_t)(n0 + r) * DD + k0 + lcol);
            Bs[lcol + 0][r] = w.x; Bs[lcol + 1][r] = w.y;
            Bs[lcol + 2][r] = w.z; Bs[lcol + 3][r] = w.w;
        }
        __syncthreads();
#pragma unroll
        for (int k = 0; k < BK; ++k) {
            float a[TM], b[TN];
            float4 a0 = *(const float4*)&As[k][ty * 8];
            float4 a1 = *(const float4*)&As[k][ty * 8 + 4];
            a[0]=a0.x; a[1]=a0.y; a[2]=a0.z; a[3]=a0.w;
            a[4]=a1.x; a[5]=a1.y; a[6]=a1.z; a[7]=a1.w;
            float4 b0 = *(const float4*)&Bs[k][tx * 8];
            float4 b1 = *(const float4*)&Bs[k][tx * 8 + 4];
            b[0]=b0.x; b[1]=b0.y; b[2]=b0.z; b[3]=b0.w;
            b[4]=b1.x; b[5]=b1.y; b[6]=b1.z; b[7]=b1.w;
#pragma unroll
            for (int i = 0; i < TM; ++i)
#pragma unroll
                for (int j = 0; j < TN; ++j)
                    acc[i][j] = fmaf(a[i], b[j], acc[i][j]);
        }
        __syncthreads();
    }
#pragma unroll
    for (int i = 0; i < TM; ++i) {
        const size_t row = (size_t)(m0 + ty * 8 + i);
        float4 o0, o1;
        o0.x = fmaxf(ALPHA * acc[i][0], 0.f);
        o0.y = fmaxf(ALPHA * acc[i][1], 0.f);
        o0.z = fmaxf(ALPHA * acc[i][2], 0.f);
        o0.w = fmaxf(ALPHA * acc[i][3], 0.f);
        o1.x = fmaxf(ALPHA * acc[i][4], 0.f);
        o1.y = fmaxf(ALPHA * acc[i][5], 0.f);
        o1.z = fmaxf(ALPHA * acc[i][6], 0.f);
        o1.w = fmaxf(ALPHA * acc[i][7], 0.f);
        *(float4*)(C + row * EE + n0 + tx * 8)     = o0;
        *(float4*)(C + row * EE + n0 + tx * 8 + 4) = o1;
    }
}

__global__ __launch_bounds__(256)
void softmax_threshold_kernel(float* __restrict__ out)
{
    const int wave = threadIdx.x >> 6;
    const int lane = threadIdx.x & 63;
    const size_t row = (size_t)blockIdx.x * 4 + wave;
    float* p = out + row * EE;

    float z[16];
    float m = 0.f;
#pragma unroll
    for (int j = 0; j < 4; ++j) {
        float4 v = *(const float4*)(p + j * 256 + lane * 4);
        z[j*4+0] = v.x; z[j*4+1] = v.y; z[j*4+2] = v.z; z[j*4+3] = v.w;
        m = fmaxf(m, fmaxf(fmaxf(v.x, v.y), fmaxf(v.z, v.w)));
    }
#pragma unroll
    for (int off = 32; off >= 1; off >>= 1)
        m = fmaxf(m, __shfl_xor(m, off, 64));
    float e[16], sum = 0.f;
#pragma unroll
    for (int j = 0; j < 16; ++j) { e[j] = expf(z[j] - m); sum += e[j]; }
#pragma unroll
    for (int off = 32; off >= 1; off >>= 1)
        sum += __shfl_xor(sum, off, 64);
    const float thr = 0.5f * sum;
#pragma unroll
    for (int j = 0; j < 4; ++j) {
        float4 o;
        o.x = (e[j*4+0] > thr) ? 1.f : 0.f;
        o.y = (e[j*4+1] > thr) ? 1.f : 0.f;
        o.z = (e[j*4+2] > thr) ? 1.f : 0.f;
        o.w = (e[j*4+3] > thr) ? 1.f : 0.f;
        *(float4*)(p + j * 256 + lane * 4) = o;
    }
}

// ---------------- launch ----------------
extern "C" void kernel_launch(void* const* d_in, const int* in_sizes, int n_in,
                              void* d_out, int out_size, void* d_ws, size_t ws_size,
                              hipStream_t stream) {
    const float* node = (const float*)d_in[1];  // [S, N, D]
    const float* edge = (const float*)d_in[2];  // [S, E, D]
    float* out = (float*)d_out;                 // [S, N, E]

    const size_t SAe = (size_t)SS * NN * DD;    // node elems
    const size_t SBe = (size_t)SS * EE * DD;    // edge elems
    const size_t split_bytes = (SAe + 2 * SBe) * 2;   // Ah + Bh + Bl
    const size_t wl_bytes    = (size_t)(SS * NN + 1) * 4;
    const size_t base_need   = split_bytes + wl_bytes;

    if (ws_size >= base_need) {
        unsigned short* Ah = (unsigned short*)d_ws;
        unsigned short* Bh = Ah + SAe;
        unsigned short* Bl = Bh + SBe;
        int* count    = (int*)(Bl + SBe);
        int* worklist = count + 1;

        // z-scratch for the parallel fixup, after the base region (256B aligned)
        const size_t zoff = (base_need + 255) & ~(size_t)255;
        int zcap = 0;
        if (ws_size > zoff) {
            size_t zc = (ws_size - zoff) / ((size_t)EE * 4);
            zcap = (int)(zc > 4096 ? 4096 : zc);
        }
        float* zbuf = (float*)((char*)d_ws + zoff);

        const int n4 = (int)((SAe + SBe) / 4);
        split_both_kernel<<<(n4 + 255) / 256, 256, 0, stream>>>(node, edge, Ah, Bh, Bl);

        zero_count_kernel<<<1, 64, 0, stream>>>(count);

        dim3 g1(NN / 128, EE / 128, SS);   // (64, 8, 3): m-fastest, A-panel on one XCD
        gemm_mfma_kernel<<<g1, 256, 0, stream>>>(Ah, Bh, Bl, out);

        softmax_threshold_flag_kernel<<<(SS * NN) / 4, 256, 0, stream>>>(out, count, worklist);

        if (zcap > 0) {
            fixup_z_kernel<<<1024, 256, 0, stream>>>(node, edge, count, worklist, zbuf, zcap);
            fixup_finish_kernel<<<64, 256, 0, stream>>>(zbuf, count, worklist, out, zcap);
        }
        // rows beyond zcap (never in practice): slow in-block path
        fixup2_kernel<<<512, 256, 0, stream>>>(node, edge, count, worklist, out, zcap);
    } else {
        dim3 g1(EE / BN, NN / BM, SS);
        gemm_relu_kernel<<<g1, 256, 0, stream>>>(node, edge, out);
        softmax_threshold_kernel<<<(SS * NN) / 4, 256, 0, stream>>>(out);
    }
}

// Round 11
// 147.205 us; speedup vs baseline: 29.8787x; 29.8787x over previous
//
#include <hip/hip_runtime.h>
#include <cmath>

// Problem constants (fixed by reference)
#define SS 3
#define NN 8192
#define EE 1024
#define DD 512
#define ALPHA 3.0f
// z-margin below which a row is recomputed in fp32.
// 3-term split-bf16 z-error sigma ~= 3e-4..5e-4; 0.03 is >= 60 sigma.
// NOTE (round-10 lesson): TAU must be << log(2)=0.693 -- the row max sits at
// z_max - T = log2 - log(sum_rel), so TAU >= log2 flags EVERY row.
// Measured rounds 3-5: ~12 flagged rows of 24576 at TAU=0.03.
#define TAU 0.03f

typedef __attribute__((ext_vector_type(8))) short bf16x8;
typedef __attribute__((ext_vector_type(4))) float f32x4;

#define AS1(p) ((const __attribute__((address_space(1))) void*)(p))
#define AS3(p) ((__attribute__((address_space(3))) void*)(p))

// ---------------- helpers ----------------
__device__ __forceinline__ unsigned short f2bf(float x) {
    unsigned u = __float_as_uint(x);
    return (unsigned short)((u + 0x7fffu + ((u >> 16) & 1u)) >> 16);
}
__device__ __forceinline__ float bf2f(unsigned short h) {
    return __uint_as_float(((unsigned)h) << 16);
}

__device__ __forceinline__ void gload_lds16(const unsigned short* g, unsigned short* l) {
    __builtin_amdgcn_global_load_lds(AS1(g), AS3(l), 16, 0, 0);
}

// ---------------- kernel A: fused fp32 -> (hi, lo) bf16 split for both inputs ----
// Also zeroes the worklist counter (block 0, thread 0) -- saves a launch.
__global__ __launch_bounds__(256)
void split_both_kernel(const float* __restrict__ node, const float* __restrict__ edge,
                       unsigned short* __restrict__ Ah, unsigned short* __restrict__ Al,
                       unsigned short* __restrict__ Bh, unsigned short* __restrict__ Bl,
                       int* __restrict__ count)
{
    if (blockIdx.x == 0 && threadIdx.x == 0) count[0] = 0;

    const int nA = SS * NN * DD / 4;
    const int nB = SS * EE * DD / 4;
    int i = blockIdx.x * blockDim.x + threadIdx.x;

    const float4* src;
    unsigned short* hi;
    unsigned short* lo;
    int idx;
    if (i < nA) {
        src = (const float4*)node; hi = Ah; lo = Al; idx = i;
    } else if (i < nA + nB) {
        src = (const float4*)edge; hi = Bh; lo = Bl; idx = i - nA;
    } else {
        return;
    }
    float4 v = src[idx];
    ushort4 h, l;
    h.x = f2bf(v.x); l.x = f2bf(v.x - bf2f(h.x));
    h.y = f2bf(v.y); l.y = f2bf(v.y - bf2f(h.y));
    h.z = f2bf(v.z); l.z = f2bf(v.z - bf2f(h.z));
    h.w = f2bf(v.w); l.w = f2bf(v.w - bf2f(h.w));
    ((ushort4*)hi)[idx] = h;
    ((ushort4*)lo)[idx] = l;
}

// ---------------- kernel B: split-bf16 MFMA GEMM, z = relu(alpha*sim) ----------------
// Round-5 VERIFIED kernel (95.5 us, MfmaUtil 35%, 0 bank conflicts, FETCH 49MB):
// 128x128 tile, BK=32, 4 waves (each 64x64 -> 4x4 16x16 MFMA frags),
// 3 MFMAs per frag position: ah*bh + ah*bl + al*bh (fp32 accumulate).
// Grid is m-fastest so all 8 n-blocks of an A-panel land on one XCD (L2 reuse).
// LDS: per tile row, 8 interleaved 16B chunks (4 hi + 4 lo), slot = j ^ (row&7):
// linear gload_lds dest + pre-swizzled global source (both-sides-or-neither),
// read back with the same XOR -> 2 lanes/bank (conflict-free).
__global__ __launch_bounds__(256)
void gemm_mfma_kernel(const unsigned short* __restrict__ Ah,
                      const unsigned short* __restrict__ Al,
                      const unsigned short* __restrict__ Bh,
                      const unsigned short* __restrict__ Bl,
                      float* __restrict__ out)
{
    const int s  = blockIdx.z;
    const int m0 = blockIdx.x * 128;   // m-fastest for XCD A-panel locality
    const int n0 = blockIdx.y * 128;

    const unsigned short* pAh = Ah + (size_t)s * NN * DD;
    const unsigned short* pAl = Al + (size_t)s * NN * DD;
    const unsigned short* pBh = Bh + (size_t)s * EE * DD;
    const unsigned short* pBl = Bl + (size_t)s * EE * DD;
    float* C = out + (size_t)s * NN * EE;

    // 2 planes (A,B) of [128 rows][8 chunks][8 ushorts] = 2 x 16KB
    __shared__ unsigned short lds[2 * 1024 * 8];

    const int t    = threadIdx.x;
    const int lane = t & 63;
    const int wid  = t >> 6;
    const int wm   = wid >> 1;       // wave row (0..1)
    const int wn   = wid & 1;        // wave col (0..1)
    const int fr   = lane & 15;      // row within 16x16 frag
    const int kg   = lane >> 4;      // k-group (0..3), 8 bf16 each

    f32x4 acc[4][4];
#pragma unroll
    for (int i = 0; i < 4; ++i)
#pragma unroll
        for (int j = 0; j < 4; ++j) acc[i][j] = (f32x4){0.f, 0.f, 0.f, 0.f};

    for (int k0 = 0; k0 < DD; k0 += 32) {
        // stage 2048 chunks of 16B (A: 0..1023, B: 1024..2047), 8 per thread.
        // LDS dest linear in chunk id; global source picks chunk j = slot ^ (row&7),
        // j<4 -> hi chunk j, j>=4 -> lo chunk j-4.
#pragma unroll
        for (int i = 0; i < 8; ++i) {
            const int c    = i * 256 + t;
            const int pc   = c & 1023;
            const int row  = pc >> 3;
            const int slot = pc & 7;
            const int j    = slot ^ (row & 7);
            const unsigned short* src;
            if (c < 1024) {
                src = (j < 4) ? pAh + (size_t)(m0 + row) * DD + k0 + j * 8
                              : pAl + (size_t)(m0 + row) * DD + k0 + (j - 4) * 8;
            } else {
                src = (j < 4) ? pBh + (size_t)(n0 + row) * DD + k0 + j * 8
                              : pBl + (size_t)(n0 + row) * DD + k0 + (j - 4) * 8;
            }
            gload_lds16(src, &lds[c * 8]);
        }
        __syncthreads();

        bf16x8 ah[4], al[4], bh[4], bl[4];
#pragma unroll
        for (int i = 0; i < 4; ++i) {
            const int r = wm * 64 + i * 16 + fr;
            ah[i] = *(const bf16x8*)&lds[r * 64 + ((kg)     ^ (r & 7)) * 8];
            al[i] = *(const bf16x8*)&lds[r * 64 + ((4 + kg) ^ (r & 7)) * 8];
        }
#pragma unroll
        for (int j = 0; j < 4; ++j) {
            const int r = wn * 64 + j * 16 + fr;
            bh[j] = *(const bf16x8*)&lds[8192 + r * 64 + ((kg)     ^ (r & 7)) * 8];
            bl[j] = *(const bf16x8*)&lds[8192 + r * 64 + ((4 + kg) ^ (r & 7)) * 8];
        }
#pragma unroll
        for (int i = 0; i < 4; ++i)
#pragma unroll
            for (int j = 0; j < 4; ++j) {
                acc[i][j] = __builtin_amdgcn_mfma_f32_16x16x32_bf16(ah[i], bh[j], acc[i][j], 0, 0, 0);
                acc[i][j] = __builtin_amdgcn_mfma_f32_16x16x32_bf16(ah[i], bl[j], acc[i][j], 0, 0, 0);
                acc[i][j] = __builtin_amdgcn_mfma_f32_16x16x32_bf16(al[i], bh[j], acc[i][j], 0, 0, 0);
            }
        __syncthreads();
    }

    // epilogue: z = relu(alpha * acc); C/D layout: col=lane&15, row=(lane>>4)*4+reg
#pragma unroll
    for (int i = 0; i < 4; ++i)
#pragma unroll
        for (int j = 0; j < 4; ++j) {
            const int col = n0 + wn * 64 + j * 16 + fr;
#pragma unroll
            for (int r = 0; r < 4; ++r) {
                const int row = m0 + wm * 64 + i * 16 + kg * 4 + r;
                C[(size_t)row * EE + col] = fmaxf(ALPHA * acc[i][j][r], 0.f);
            }
        }
}

// ---------------- kernel C: softmax threshold + borderline worklist ----------------
// One wave per 1024-wide row; in-place z -> binary; rows with any |z-T|<TAU
// are appended to worklist for exact fp32 recompute.
__global__ __launch_bounds__(256)
void softmax_threshold_flag_kernel(float* __restrict__ out,
                                   int* __restrict__ count,
                                   int* __restrict__ worklist)
{
    const int wave = threadIdx.x >> 6;
    const int lane = threadIdx.x & 63;
    const size_t row = (size_t)blockIdx.x * 4 + wave;
    float* p = out + row * EE;

    float z[16];
    float m = 0.f;  // z >= 0 (relu output)
#pragma unroll
    for (int j = 0; j < 4; ++j) {
        float4 v = *(const float4*)(p + j * 256 + lane * 4);
        z[j*4+0] = v.x; z[j*4+1] = v.y; z[j*4+2] = v.z; z[j*4+3] = v.w;
        m = fmaxf(m, fmaxf(fmaxf(v.x, v.y), fmaxf(v.z, v.w)));
    }
#pragma unroll
    for (int off = 32; off >= 1; off >>= 1)
        m = fmaxf(m, __shfl_xor(m, off, 64));

    float e[16];
    float sum = 0.f;
#pragma unroll
    for (int j = 0; j < 16; ++j) {
        e[j] = expf(z[j] - m);
        sum += e[j];
    }
#pragma unroll
    for (int off = 32; off >= 1; off >>= 1)
        sum += __shfl_xor(sum, off, 64);

    const float thr = 0.5f * sum;
    const float T   = m + logf(thr);   // z-space threshold
    int lf = 0;
#pragma unroll
    for (int j = 0; j < 16; ++j)
        lf |= (fabsf(z[j] - T) < TAU) ? 1 : 0;

#pragma unroll
    for (int j = 0; j < 4; ++j) {
        float4 o;
        o.x = (e[j*4+0] > thr) ? 1.f : 0.f;
        o.y = (e[j*4+1] > thr) ? 1.f : 0.f;
        o.z = (e[j*4+2] > thr) ? 1.f : 0.f;
        o.w = (e[j*4+3] > thr) ? 1.f : 0.f;
        *(float4*)(p + j * 256 + lane * 4) = o;
    }
    const int anyf = __any(lf);
    if (anyf && lane == 0) {
        int idx = atomicAdd(count, 1);
        worklist[idx] = (int)row;
    }
}

// ---------------- kernel D1: parallel fp32 z-recompute of worklisted rows ----
// Work item = (worklist row, 256-col chunk): 4 blocks per flagged row.
// Summation order IDENTICAL to verified fixup2: va0/va1 fmaf chain + butterfly.
__global__ __launch_bounds__(256)
void fixup_z_kernel(const float* __restrict__ node, const float* __restrict__ edge,
                    const int* __restrict__ count, const int* __restrict__ worklist,
                    float* __restrict__ zbuf, int zcap)
{
    __shared__ float sa[DD];
    const int t    = threadIdx.x;
    const int lane = t & 63;
    const int wid  = t >> 6;

    int nwork = count[0];
    if (nwork > zcap) nwork = zcap;
    const int items = nwork * 4;

    for (int item = blockIdx.x; item < items; item += gridDim.x) {
        const int w   = item >> 2;
        const int row = worklist[w];
        const int c0  = (item & 3) * 256;
        const int s   = row / NN;
        const float* a = node + (size_t)row * DD;
        const float* B = edge + (size_t)s * EE * DD;

        __syncthreads();   // protect sa from previous item
        if (t < DD / 4) ((float4*)sa)[t] = ((const float4*)a)[t];
        __syncthreads();

        const float4 va0 = ((const float4*)sa)[lane];
        const float4 va1 = ((const float4*)sa)[64 + lane];

        const int cbase = c0 + wid * 64;
        for (int g = 0; g < 16; ++g) {
            float acc[4];
#pragma unroll
            for (int j = 0; j < 4; ++j) {
                const float* b = B + (size_t)(cbase + g * 4 + j) * DD;
                float4 b0 = *(const float4*)(b + lane * 4);
                float4 b1 = *(const float4*)(b + 256 + lane * 4);
                float av;
                av = va0.x * b0.x;
                av = fmaf(va0.y, b0.y, av);
                av = fmaf(va0.z, b0.z, av);
                av = fmaf(va0.w, b0.w, av);
                av = fmaf(va1.x, b1.x, av);
                av = fmaf(va1.y, b1.y, av);
                av = fmaf(va1.z, b1.z, av);
                av = fmaf(va1.w, b1.w, av);
                acc[j] = av;
            }
#pragma unroll
            for (int off = 32; off >= 1; off >>= 1) {
#pragma unroll
                for (int j = 0; j < 4; ++j)
                    acc[j] += __shfl_xor(acc[j], off, 64);
            }
            if (lane == 0) {
#pragma unroll
                for (int j = 0; j < 4; ++j)
                    zbuf[(size_t)w * EE + cbase + g * 4 + j] = fmaxf(ALPHA * acc[j], 0.f);
            }
        }
    }
}

// ---------------- kernel D2: softmax+threshold of recomputed rows ----------
__global__ __launch_bounds__(256)
void fixup_finish_kernel(const float* __restrict__ zbuf,
                         const int* __restrict__ count, const int* __restrict__ worklist,
                         float* __restrict__ out, int zcap)
{
    const int lane = threadIdx.x & 63;
    const int wid  = threadIdx.x >> 6;
    int nwork = count[0];
    if (nwork > zcap) nwork = zcap;

    for (int w = blockIdx.x * 4 + wid; w < nwork; w += gridDim.x * 4) {
        const int row = worklist[w];
        const float* p = zbuf + (size_t)w * EE;

        float z[16];
        float m = 0.f;
#pragma unroll
        for (int j = 0; j < 4; ++j) {
            float4 v = *(const float4*)(p + j * 256 + lane * 4);
            z[j*4+0] = v.x; z[j*4+1] = v.y; z[j*4+2] = v.z; z[j*4+3] = v.w;
            m = fmaxf(m, fmaxf(fmaxf(v.x, v.y), fmaxf(v.z, v.w)));
        }
#pragma unroll
        for (int off = 32; off >= 1; off >>= 1)
            m = fmaxf(m, __shfl_xor(m, off, 64));

        float e[16], sum = 0.f;
#pragma unroll
        for (int j = 0; j < 16; ++j) { e[j] = expf(z[j] - m); sum += e[j]; }
#pragma unroll
        for (int off = 32; off >= 1; off >>= 1)
            sum += __shfl_xor(sum, off, 64);

        const float thr = 0.5f * sum;
        float* q = out + (size_t)row * EE;
#pragma unroll
        for (int j = 0; j < 4; ++j) {
            float4 o;
            o.x = (e[j*4+0] > thr) ? 1.f : 0.f;
            o.y = (e[j*4+1] > thr) ? 1.f : 0.f;
            o.z = (e[j*4+2] > thr) ? 1.f : 0.f;
            o.w = (e[j*4+3] > thr) ? 1.f : 0.f;
            *(float4*)(q + j * 256 + lane * 4) = o;
        }
    }
}

// ---------------- kernel D3: slow-path fixup for rows beyond zcap ----------
// (empty in practice; correctness net for worklist overflow)
__global__ __launch_bounds__(256)
void fixup2_kernel(const float* __restrict__ node, const float* __restrict__ edge,
                   const int* __restrict__ count, const int* __restrict__ worklist,
                   float* __restrict__ out, int start)
{
    __shared__ float sa[DD];
    __shared__ float zrow[EE];
    __shared__ float red[8];

    const int t    = threadIdx.x;
    const int lane = t & 63;
    const int wid  = t >> 6;
    const int nwork = count[0];

    for (int w = start + blockIdx.x; w < nwork; w += gridDim.x) {
        const int row = worklist[w];
        const int s = row / NN;
        const float* a = node + (size_t)row * DD;
        const float* B = edge + (size_t)s * EE * DD;

        __syncthreads();
        if (t < DD / 4) ((float4*)sa)[t] = ((const float4*)a)[t];
        __syncthreads();

        float4 va0 = ((const float4*)sa)[lane];
        float4 va1 = ((const float4*)sa)[64 + lane];

        for (int c = wid; c < EE; c += 4) {
            const float* b = B + (size_t)c * DD;
            float4 b0 = *(const float4*)(b + lane * 4);
            float4 b1 = *(const float4*)(b + 256 + lane * 4);
            float acc;
            acc = va0.x * b0.x;
            acc = fmaf(va0.y, b0.y, acc);
            acc = fmaf(va0.z, b0.z, acc);
            acc = fmaf(va0.w, b0.w, acc);
            acc = fmaf(va1.x, b1.x, acc);
            acc = fmaf(va1.y, b1.y, acc);
            acc = fmaf(va1.z, b1.z, acc);
            acc = fmaf(va1.w, b1.w, acc);
#pragma unroll
            for (int off = 32; off >= 1; off >>= 1)
                acc += __shfl_xor(acc, off, 64);
            if (lane == 0) zrow[c] = fmaxf(ALPHA * acc, 0.f);
        }
        __syncthreads();

        float z[4], m = 0.f;
#pragma unroll
        for (int j = 0; j < 4; ++j) {
            z[j] = zrow[j * 256 + t];
            m = fmaxf(m, z[j]);
        }
#pragma unroll
        for (int off = 32; off >= 1; off >>= 1)
            m = fmaxf(m, __shfl_xor(m, off, 64));
        if (lane == 0) red[wid] = m;
        __syncthreads();
        m = fmaxf(fmaxf(red[0], red[1]), fmaxf(red[2], red[3]));

        float e[4], sum = 0.f;
#pragma unroll
        for (int j = 0; j < 4; ++j) { e[j] = expf(z[j] - m); sum += e[j]; }
#pragma unroll
        for (int off = 32; off >= 1; off >>= 1)
            sum += __shfl_xor(sum, off, 64);
        if (lane == 0) red[4 + wid] = sum;
        __syncthreads();
        sum = red[4] + red[5] + red[6] + red[7];

        const float thr = 0.5f * sum;
#pragma unroll
        for (int j = 0; j < 4; ++j)
            out[(size_t)row * EE + j * 256 + t] = (e[j] > thr) ? 1.f : 0.f;
        __syncthreads();
    }
}

// ---------------- fallback fp32 path (round-0, verified) ----------------
#define BM 128
#define BN 128
#define BK 16
#define TM 8
#define TN 8

__global__ __launch_bounds__(256, 2)
void gemm_relu_kernel(const float* __restrict__ node,
                      const float* __restrict__ edge,
                      float* __restrict__ out)
{
    const int s  = blockIdx.z;
    const int m0 = blockIdx.y * BM;
    const int n0 = blockIdx.x * BN;

    const float* A = node + (size_t)s * NN * DD;
    const float* B = edge + (size_t)s * EE * DD;
    float*       C = out  + (size_t)s * NN * EE;

    __shared__ float As[BK][BM + 4];
    __shared__ float Bs[BK][BN + 4];

    const int tid = threadIdx.x;
    const int tx  = tid % 16;
    const int ty  = tid / 16;
    const int lrow = tid / 4;
    const int lcol = (tid % 4) * 4;

    float acc[TM][TN];
#pragma unroll
    for (int i = 0; i < TM; ++i)
#pragma unroll
        for (int j = 0; j < TN; ++j) acc[i][j] = 0.f;

    for (int k0 = 0; k0 < DD; k0 += BK) {
#pragma unroll
        for (int p = 0; p < 2; ++p) {
            const int r = lrow + p * 64;
            float4 v = *(const float4*)(A + (size_t)(m0 + r) * DD + k0 + lcol);
            As[lcol + 0][r] = v.x; As[lcol + 1][r] = v.y;
            As[lcol + 2][r] = v.z; As[lcol + 3][r] = v.w;
            float4 w = *(const float4*)(B + (size_t)(n0 + r) * DD + k0 + lcol);
            Bs[lcol + 0][r] = w.x; Bs[lcol + 1][r] = w.y;
            Bs[lcol + 2][r] = w.z; Bs[lcol + 3][r] = w.w;
        }
        __syncthreads();
#pragma unroll
        for (int k = 0; k < BK; ++k) {
            float a[TM], b[TN];
            float4 a0 = *(const float4*)&As[k][ty * 8];
            float4 a1 = *(const float4*)&As[k][ty * 8 + 4];
            a[0]=a0.x; a[1]=a0.y; a[2]=a0.z; a[3]=a0.w;
            a[4]=a1.x; a[5]=a1.y; a[6]=a1.z; a[7]=a1.w;
            float4 b0 = *(const float4*)&Bs[k][tx * 8];
            float4 b1 = *(const float4*)&Bs[k][tx * 8 + 4];
            b[0]=b0.x; b[1]=b0.y; b[2]=b0.z; b[3]=b0.w;
            b[4]=b1.x; b[5]=b1.y; b[6]=b1.z; b[7]=b1.w;
#pragma unroll
            for (int i = 0; i < TM; ++i)
#pragma unroll
                for (int j = 0; j < TN; ++j)
                    acc[i][j] = fmaf(a[i], b[j], acc[i][j]);
        }
        __syncthreads();
    }
#pragma unroll
    for (int i = 0; i < TM; ++i) {
        const size_t row = (size_t)(m0 + ty * 8 + i);
        float4 o0, o1;
        o0.x = fmaxf(ALPHA * acc[i][0], 0.f);
        o0.y = fmaxf(ALPHA * acc[i][1], 0.f);
        o0.z = fmaxf(ALPHA * acc[i][2], 0.f);
        o0.w = fmaxf(ALPHA * acc[i][3], 0.f);
        o1.x = fmaxf(ALPHA * acc[i][4], 0.f);
        o1.y = fmaxf(ALPHA * acc[i][5], 0.f);
        o1.z = fmaxf(ALPHA * acc[i][6], 0.f);
        o1.w = fmaxf(ALPHA * acc[i][7], 0.f);
        *(float4*)(C + row * EE + n0 + tx * 8)     = o0;
        *(float4*)(C + row * EE + n0 + tx * 8 + 4) = o1;
    }
}

__global__ __launch_bounds__(256)
void softmax_threshold_kernel(float* __restrict__ out)
{
    const int wave = threadIdx.x >> 6;
    const int lane = threadIdx.x & 63;
    const size_t row = (size_t)blockIdx.x * 4 + wave;
    float* p = out + row * EE;

    float z[16];
    float m = 0.f;
#pragma unroll
    for (int j = 0; j < 4; ++j) {
        float4 v = *(const float4*)(p + j * 256 + lane * 4);
        z[j*4+0] = v.x; z[j*4+1] = v.y; z[j*4+2] = v.z; z[j*4+3] = v.w;
        m = fmaxf(m, fmaxf(fmaxf(v.x, v.y), fmaxf(v.z, v.w)));
    }
#pragma unroll
    for (int off = 32; off >= 1; off >>= 1)
        m = fmaxf(m, __shfl_xor(m, off, 64));
    float e[16], sum = 0.f;
#pragma unroll
    for (int j = 0; j < 16; ++j) { e[j] = expf(z[j] - m); sum += e[j]; }
#pragma unroll
    for (int off = 32; off >= 1; off >>= 1)
        sum += __shfl_xor(sum, off, 64);
    const float thr = 0.5f * sum;
#pragma unroll
    for (int j = 0; j < 4; ++j) {
        float4 o;
        o.x = (e[j*4+0] > thr) ? 1.f : 0.f;
        o.y = (e[j*4+1] > thr) ? 1.f : 0.f;
        o.z = (e[j*4+2] > thr) ? 1.f : 0.f;
        o.w = (e[j*4+3] > thr) ? 1.f : 0.f;
        *(float4*)(p + j * 256 + lane * 4) = o;
    }
}

// ---------------- launch ----------------
extern "C" void kernel_launch(void* const* d_in, const int* in_sizes, int n_in,
                              void* d_out, int out_size, void* d_ws, size_t ws_size,
                              hipStream_t stream) {
    const float* node = (const float*)d_in[1];  // [S, N, D]
    const float* edge = (const float*)d_in[2];  // [S, E, D]
    float* out = (float*)d_out;                 // [S, N, E]

    const size_t SAe = (size_t)SS * NN * DD;    // node elems
    const size_t SBe = (size_t)SS * EE * DD;    // edge elems
    const size_t split_bytes = (2 * SAe + 2 * SBe) * 2;
    const size_t wl_bytes    = (size_t)(SS * NN + 1) * 4;
    const size_t base_need   = split_bytes + wl_bytes;

    if (ws_size >= base_need) {
        unsigned short* Ah = (unsigned short*)d_ws;
        unsigned short* Al = Ah + SAe;
        unsigned short* Bh = Al + SAe;
        unsigned short* Bl = Bh + SBe;
        int* count    = (int*)(Bl + SBe);
        int* worklist = count + 1;

        // z-scratch for the parallel fixup, after the base region (256B aligned)
        const size_t zoff = (base_need + 255) & ~(size_t)255;
        int zcap = 0;
        if (ws_size > zoff) {
            size_t zc = (ws_size - zoff) / ((size_t)EE * 4);
            zcap = (int)(zc > 4096 ? 4096 : zc);
        }
        float* zbuf = (float*)((char*)d_ws + zoff);

        const int n4 = (int)((SAe + SBe) / 4);
        split_both_kernel<<<(n4 + 255) / 256, 256, 0, stream>>>(node, edge, Ah, Al, Bh, Bl, count);

        dim3 g1(NN / 128, EE / 128, SS);   // (64, 8, 3): m-fastest, A-panel on one XCD
        gemm_mfma_kernel<<<g1, 256, 0, stream>>>(Ah, Al, Bh, Bl, out);

        softmax_threshold_flag_kernel<<<(SS * NN) / 4, 256, 0, stream>>>(out, count, worklist);

        if (zcap > 0) {
            fixup_z_kernel<<<1024, 256, 0, stream>>>(node, edge, count, worklist, zbuf, zcap);
            fixup_finish_kernel<<<64, 256, 0, stream>>>(zbuf, count, worklist, out, zcap);
        }
        // rows beyond zcap (never in practice): slow in-block path
        fixup2_kernel<<<128, 256, 0, stream>>>(node, edge, count, worklist, out, zcap);
    } else {
        dim3 g1(EE / BN, NN / BM, SS);
        gemm_relu_kernel<<<g1, 256, 0, stream>>>(node, edge, out);
        softmax_threshold_kernel<<<(SS * NN) / 4, 256, 0, stream>>>(out);
    }
}

// Round 12
// 141.254 us; speedup vs baseline: 31.1373x; 1.0421x over previous
//
#include <hip/hip_runtime.h>
#include <cmath>

// Problem constants (fixed by reference)
#define SS 3
#define NN 8192
#define EE 1024
#define DD 512
#define ALPHA 3.0f
// z-margin below which a row is recomputed in fp32 (fp32-z path).
// 3-term split-bf16 z-error sigma ~= 3e-4..5e-4; 0.03 is >= 60 sigma.
// NOTE (round-10 lesson): TAU must be << log(2)=0.693 -- the row max sits at
// z_max - T = log2 - log(sum_rel), so TAU >= log2 flags EVERY row.
#define TAU 0.03f
// u16-z path: z stored as round(z*128) (quant +-0.004; T shift <= +-0.008).
// Margin > 0.012 is decision-exact; TAU16 = 0.05 is 4x that.
#define TAU16 0.05f
#define ZSCALE 128.0f

typedef __attribute__((ext_vector_type(8))) short bf16x8;
typedef __attribute__((ext_vector_type(4))) float f32x4;

#define AS1(p) ((const __attribute__((address_space(1))) void*)(p))
#define AS3(p) ((__attribute__((address_space(3))) void*)(p))

// ---------------- helpers ----------------
__device__ __forceinline__ unsigned short f2bf(float x) {
    unsigned u = __float_as_uint(x);
    return (unsigned short)((u + 0x7fffu + ((u >> 16) & 1u)) >> 16);
}
__device__ __forceinline__ float bf2f(unsigned short h) {
    return __uint_as_float(((unsigned)h) << 16);
}

__device__ __forceinline__ void gload_lds16(const unsigned short* g, unsigned short* l) {
    __builtin_amdgcn_global_load_lds(AS1(g), AS3(l), 16, 0, 0);
}

// ---------------- kernel A: fused fp32 -> (hi, lo) bf16 split for both inputs ----
// Also zeroes the worklist counter (block 0, thread 0) -- saves a launch.
__global__ __launch_bounds__(256)
void split_both_kernel(const float* __restrict__ node, const float* __restrict__ edge,
                       unsigned short* __restrict__ Ah, unsigned short* __restrict__ Al,
                       unsigned short* __restrict__ Bh, unsigned short* __restrict__ Bl,
                       int* __restrict__ count)
{
    if (blockIdx.x == 0 && threadIdx.x == 0) count[0] = 0;

    const int nA = SS * NN * DD / 4;
    const int nB = SS * EE * DD / 4;
    int i = blockIdx.x * blockDim.x + threadIdx.x;

    const float4* src;
    unsigned short* hi;
    unsigned short* lo;
    int idx;
    if (i < nA) {
        src = (const float4*)node; hi = Ah; lo = Al; idx = i;
    } else if (i < nA + nB) {
        src = (const float4*)edge; hi = Bh; lo = Bl; idx = i - nA;
    } else {
        return;
    }
    float4 v = src[idx];
    ushort4 h, l;
    h.x = f2bf(v.x); l.x = f2bf(v.x - bf2f(h.x));
    h.y = f2bf(v.y); l.y = f2bf(v.y - bf2f(h.y));
    h.z = f2bf(v.z); l.z = f2bf(v.z - bf2f(h.z));
    h.w = f2bf(v.w); l.w = f2bf(v.w - bf2f(h.w));
    ((ushort4*)hi)[idx] = h;
    ((ushort4*)lo)[idx] = l;
}

// ---------------- kernel B: split-bf16 MFMA GEMM, z = relu(alpha*sim) ----------------
// Round-5 VERIFIED kernel (95.5 us, MfmaUtil 35%, 0 bank conflicts, FETCH 49MB):
// 128x128 tile, BK=32, 4 waves (each 64x64 -> 4x4 16x16 MFMA frags),
// 3 MFMAs per frag position: ah*bh + ah*bl + al*bh (fp32 accumulate).
// Grid is m-fastest so all 8 n-blocks of an A-panel land on one XCD (L2 reuse).
// LDS: per tile row, 8 interleaved 16B chunks (4 hi + 4 lo), slot = j ^ (row&7):
// linear gload_lds dest + pre-swizzled global source (both-sides-or-neither),
// read back with the same XOR -> 2 lanes/bank (conflict-free).
// Epilogue: if z16 != nullptr write u16 z (round(z*128), 49MB); else fp32 z to out.
__global__ __launch_bounds__(256)
void gemm_mfma_kernel(const unsigned short* __restrict__ Ah,
                      const unsigned short* __restrict__ Al,
                      const unsigned short* __restrict__ Bh,
                      const unsigned short* __restrict__ Bl,
                      float* __restrict__ out,
                      unsigned short* __restrict__ z16)
{
    const int s  = blockIdx.z;
    const int m0 = blockIdx.x * 128;   // m-fastest for XCD A-panel locality
    const int n0 = blockIdx.y * 128;

    const unsigned short* pAh = Ah + (size_t)s * NN * DD;
    const unsigned short* pAl = Al + (size_t)s * NN * DD;
    const unsigned short* pBh = Bh + (size_t)s * EE * DD;
    const unsigned short* pBl = Bl + (size_t)s * EE * DD;

    // 2 planes (A,B) of [128 rows][8 chunks][8 ushorts] = 2 x 16KB
    __shared__ unsigned short lds[2 * 1024 * 8];

    const int t    = threadIdx.x;
    const int lane = t & 63;
    const int wid  = t >> 6;
    const int wm   = wid >> 1;       // wave row (0..1)
    const int wn   = wid & 1;        // wave col (0..1)
    const int fr   = lane & 15;      // row within 16x16 frag
    const int kg   = lane >> 4;      // k-group (0..3), 8 bf16 each

    f32x4 acc[4][4];
#pragma unroll
    for (int i = 0; i < 4; ++i)
#pragma unroll
        for (int j = 0; j < 4; ++j) acc[i][j] = (f32x4){0.f, 0.f, 0.f, 0.f};

    for (int k0 = 0; k0 < DD; k0 += 32) {
        // stage 2048 chunks of 16B (A: 0..1023, B: 1024..2047), 8 per thread.
        // LDS dest linear in chunk id; global source picks chunk j = slot ^ (row&7),
        // j<4 -> hi chunk j, j>=4 -> lo chunk j-4.
#pragma unroll
        for (int i = 0; i < 8; ++i) {
            const int c    = i * 256 + t;
            const int pc   = c & 1023;
            const int row  = pc >> 3;
            const int slot = pc & 7;
            const int j    = slot ^ (row & 7);
            const unsigned short* src;
            if (c < 1024) {
                src = (j < 4) ? pAh + (size_t)(m0 + row) * DD + k0 + j * 8
                              : pAl + (size_t)(m0 + row) * DD + k0 + (j - 4) * 8;
            } else {
                src = (j < 4) ? pBh + (size_t)(n0 + row) * DD + k0 + j * 8
                              : pBl + (size_t)(n0 + row) * DD + k0 + (j - 4) * 8;
            }
            gload_lds16(src, &lds[c * 8]);
        }
        __syncthreads();

        bf16x8 ah[4], al[4], bh[4], bl[4];
#pragma unroll
        for (int i = 0; i < 4; ++i) {
            const int r = wm * 64 + i * 16 + fr;
            ah[i] = *(const bf16x8*)&lds[r * 64 + ((kg)     ^ (r & 7)) * 8];
            al[i] = *(const bf16x8*)&lds[r * 64 + ((4 + kg) ^ (r & 7)) * 8];
        }
#pragma unroll
        for (int j = 0; j < 4; ++j) {
            const int r = wn * 64 + j * 16 + fr;
            bh[j] = *(const bf16x8*)&lds[8192 + r * 64 + ((kg)     ^ (r & 7)) * 8];
            bl[j] = *(const bf16x8*)&lds[8192 + r * 64 + ((4 + kg) ^ (r & 7)) * 8];
        }
#pragma unroll
        for (int i = 0; i < 4; ++i)
#pragma unroll
            for (int j = 0; j < 4; ++j) {
                acc[i][j] = __builtin_amdgcn_mfma_f32_16x16x32_bf16(ah[i], bh[j], acc[i][j], 0, 0, 0);
                acc[i][j] = __builtin_amdgcn_mfma_f32_16x16x32_bf16(ah[i], bl[j], acc[i][j], 0, 0, 0);
                acc[i][j] = __builtin_amdgcn_mfma_f32_16x16x32_bf16(al[i], bh[j], acc[i][j], 0, 0, 0);
            }
        __syncthreads();
    }

    // epilogue: z = relu(alpha * acc); C/D layout: col=lane&15, row=(lane>>4)*4+reg
    if (z16 != nullptr) {
        unsigned short* Z = z16 + (size_t)s * NN * EE;
#pragma unroll
        for (int i = 0; i < 4; ++i)
#pragma unroll
            for (int j = 0; j < 4; ++j) {
                const int col = n0 + wn * 64 + j * 16 + fr;
#pragma unroll
                for (int r = 0; r < 4; ++r) {
                    const int row = m0 + wm * 64 + i * 16 + kg * 4 + r;
                    float z = fmaxf(ALPHA * acc[i][j][r], 0.f);
                    unsigned u = (unsigned)(z * ZSCALE + 0.5f);
                    Z[(size_t)row * EE + col] = (unsigned short)(u > 65535u ? 65535u : u);
                }
            }
    } else {
        float* C = out + (size_t)s * NN * EE;
#pragma unroll
        for (int i = 0; i < 4; ++i)
#pragma unroll
            for (int j = 0; j < 4; ++j) {
                const int col = n0 + wn * 64 + j * 16 + fr;
#pragma unroll
                for (int r = 0; r < 4; ++r) {
                    const int row = m0 + wm * 64 + i * 16 + kg * 4 + r;
                    C[(size_t)row * EE + col] = fmaxf(ALPHA * acc[i][j][r], 0.f);
                }
            }
    }
}

// ---------------- kernel C16: softmax threshold from u16 z + worklist ----------------
// One wave per row; reads u16 z (49MB), writes binary fp32 to out (100MB).
__global__ __launch_bounds__(256)
void softmax_threshold_flag16_kernel(const unsigned short* __restrict__ z16,
                                     float* __restrict__ out,
                                     int* __restrict__ count,
                                     int* __restrict__ worklist)
{
    const int wave = threadIdx.x >> 6;
    const int lane = threadIdx.x & 63;
    const size_t row = (size_t)blockIdx.x * 4 + wave;
    const unsigned short* p = z16 + row * EE;

    float z[16];
    float m = 0.f;  // z >= 0 (relu output)
#pragma unroll
    for (int j = 0; j < 4; ++j) {
        ushort4 v = *(const ushort4*)(p + j * 256 + lane * 4);
        z[j*4+0] = (float)v.x * (1.0f / ZSCALE);
        z[j*4+1] = (float)v.y * (1.0f / ZSCALE);
        z[j*4+2] = (float)v.z * (1.0f / ZSCALE);
        z[j*4+3] = (float)v.w * (1.0f / ZSCALE);
        m = fmaxf(m, fmaxf(fmaxf(z[j*4+0], z[j*4+1]), fmaxf(z[j*4+2], z[j*4+3])));
    }
#pragma unroll
    for (int off = 32; off >= 1; off >>= 1)
        m = fmaxf(m, __shfl_xor(m, off, 64));

    float e[16];
    float sum = 0.f;
#pragma unroll
    for (int j = 0; j < 16; ++j) {
        e[j] = expf(z[j] - m);
        sum += e[j];
    }
#pragma unroll
    for (int off = 32; off >= 1; off >>= 1)
        sum += __shfl_xor(sum, off, 64);

    const float thr = 0.5f * sum;
    const float T   = m + logf(thr);   // z-space threshold
    int lf = 0;
#pragma unroll
    for (int j = 0; j < 16; ++j)
        lf |= (fabsf(z[j] - T) < TAU16) ? 1 : 0;

    float* q = out + row * EE;
#pragma unroll
    for (int j = 0; j < 4; ++j) {
        float4 o;
        o.x = (e[j*4+0] > thr) ? 1.f : 0.f;
        o.y = (e[j*4+1] > thr) ? 1.f : 0.f;
        o.z = (e[j*4+2] > thr) ? 1.f : 0.f;
        o.w = (e[j*4+3] > thr) ? 1.f : 0.f;
        *(float4*)(q + j * 256 + lane * 4) = o;
    }
    const int anyf = __any(lf);
    if (anyf && lane == 0) {
        int idx = atomicAdd(count, 1);
        worklist[idx] = (int)row;
    }
}

// ---------------- kernel C: fp32-z softmax threshold + worklist (fallback) --------
__global__ __launch_bounds__(256)
void softmax_threshold_flag_kernel(float* __restrict__ out,
                                   int* __restrict__ count,
                                   int* __restrict__ worklist)
{
    const int wave = threadIdx.x >> 6;
    const int lane = threadIdx.x & 63;
    const size_t row = (size_t)blockIdx.x * 4 + wave;
    float* p = out + row * EE;

    float z[16];
    float m = 0.f;  // z >= 0 (relu output)
#pragma unroll
    for (int j = 0; j < 4; ++j) {
        float4 v = *(const float4*)(p + j * 256 + lane * 4);
        z[j*4+0] = v.x; z[j*4+1] = v.y; z[j*4+2] = v.z; z[j*4+3] = v.w;
        m = fmaxf(m, fmaxf(fmaxf(v.x, v.y), fmaxf(v.z, v.w)));
    }
#pragma unroll
    for (int off = 32; off >= 1; off >>= 1)
        m = fmaxf(m, __shfl_xor(m, off, 64));

    float e[16];
    float sum = 0.f;
#pragma unroll
    for (int j = 0; j < 16; ++j) {
        e[j] = expf(z[j] - m);
        sum += e[j];
    }
#pragma unroll
    for (int off = 32; off >= 1; off >>= 1)
        sum += __shfl_xor(sum, off, 64);

    const float thr = 0.5f * sum;
    const float T   = m + logf(thr);
    int lf = 0;
#pragma unroll
    for (int j = 0; j < 16; ++j)
        lf |= (fabsf(z[j] - T) < TAU) ? 1 : 0;

#pragma unroll
    for (int j = 0; j < 4; ++j) {
        float4 o;
        o.x = (e[j*4+0] > thr) ? 1.f : 0.f;
        o.y = (e[j*4+1] > thr) ? 1.f : 0.f;
        o.z = (e[j*4+2] > thr) ? 1.f : 0.f;
        o.w = (e[j*4+3] > thr) ? 1.f : 0.f;
        *(float4*)(p + j * 256 + lane * 4) = o;
    }
    const int anyf = __any(lf);
    if (anyf && lane == 0) {
        int idx = atomicAdd(count, 1);
        worklist[idx] = (int)row;
    }
}

// ---------------- kernel D1: parallel fp32 z-recompute of worklisted rows ----
// Work item = (worklist row, 256-col chunk): 4 blocks per flagged row.
// Summation order IDENTICAL to verified fixup2: va0/va1 fmaf chain + butterfly.
__global__ __launch_bounds__(256)
void fixup_z_kernel(const float* __restrict__ node, const float* __restrict__ edge,
                    const int* __restrict__ count, const int* __restrict__ worklist,
                    float* __restrict__ zbuf, int zcap)
{
    __shared__ float sa[DD];
    const int t    = threadIdx.x;
    const int lane = t & 63;
    const int wid  = t >> 6;

    int nwork = count[0];
    if (nwork > zcap) nwork = zcap;
    const int items = nwork * 4;

    for (int item = blockIdx.x; item < items; item += gridDim.x) {
        const int w   = item >> 2;
        const int row = worklist[w];
        const int c0  = (item & 3) * 256;
        const int s   = row / NN;
        const float* a = node + (size_t)row * DD;
        const float* B = edge + (size_t)s * EE * DD;

        __syncthreads();   // protect sa from previous item
        if (t < DD / 4) ((float4*)sa)[t] = ((const float4*)a)[t];
        __syncthreads();

        const float4 va0 = ((const float4*)sa)[lane];
        const float4 va1 = ((const float4*)sa)[64 + lane];

        const int cbase = c0 + wid * 64;
        for (int g = 0; g < 16; ++g) {
            float acc[4];
#pragma unroll
            for (int j = 0; j < 4; ++j) {
                const float* b = B + (size_t)(cbase + g * 4 + j) * DD;
                float4 b0 = *(const float4*)(b + lane * 4);
                float4 b1 = *(const float4*)(b + 256 + lane * 4);
                float av;
                av = va0.x * b0.x;
                av = fmaf(va0.y, b0.y, av);
                av = fmaf(va0.z, b0.z, av);
                av = fmaf(va0.w, b0.w, av);
                av = fmaf(va1.x, b1.x, av);
                av = fmaf(va1.y, b1.y, av);
                av = fmaf(va1.z, b1.z, av);
                av = fmaf(va1.w, b1.w, av);
                acc[j] = av;
            }
#pragma unroll
            for (int off = 32; off >= 1; off >>= 1) {
#pragma unroll
                for (int j = 0; j < 4; ++j)
                    acc[j] += __shfl_xor(acc[j], off, 64);
            }
            if (lane == 0) {
#pragma unroll
                for (int j = 0; j < 4; ++j)
                    zbuf[(size_t)w * EE + cbase + g * 4 + j] = fmaxf(ALPHA * acc[j], 0.f);
            }
        }
    }
}

// ---------------- kernel D2: softmax+threshold of recomputed rows ----------
__global__ __launch_bounds__(256)
void fixup_finish_kernel(const float* __restrict__ zbuf,
                         const int* __restrict__ count, const int* __restrict__ worklist,
                         float* __restrict__ out, int zcap)
{
    const int lane = threadIdx.x & 63;
    const int wid  = threadIdx.x >> 6;
    int nwork = count[0];
    if (nwork > zcap) nwork = zcap;

    for (int w = blockIdx.x * 4 + wid; w < nwork; w += gridDim.x * 4) {
        const int row = worklist[w];
        const float* p = zbuf + (size_t)w * EE;

        float z[16];
        float m = 0.f;
#pragma unroll
        for (int j = 0; j < 4; ++j) {
            float4 v = *(const float4*)(p + j * 256 + lane * 4);
            z[j*4+0] = v.x; z[j*4+1] = v.y; z[j*4+2] = v.z; z[j*4+3] = v.w;
            m = fmaxf(m, fmaxf(fmaxf(v.x, v.y), fmaxf(v.z, v.w)));
        }
#pragma unroll
        for (int off = 32; off >= 1; off >>= 1)
            m = fmaxf(m, __shfl_xor(m, off, 64));

        float e[16], sum = 0.f;
#pragma unroll
        for (int j = 0; j < 16; ++j) { e[j] = expf(z[j] - m); sum += e[j]; }
#pragma unroll
        for (int off = 32; off >= 1; off >>= 1)
            sum += __shfl_xor(sum, off, 64);

        const float thr = 0.5f * sum;
        float* q = out + (size_t)row * EE;
#pragma unroll
        for (int j = 0; j < 4; ++j) {
            float4 o;
            o.x = (e[j*4+0] > thr) ? 1.f : 0.f;
            o.y = (e[j*4+1] > thr) ? 1.f : 0.f;
            o.z = (e[j*4+2] > thr) ? 1.f : 0.f;
            o.w = (e[j*4+3] > thr) ? 1.f : 0.f;
            *(float4*)(q + j * 256 + lane * 4) = o;
        }
    }
}

// ---------------- kernel D3: slow-path fixup for rows beyond zcap ----------
// (empty in practice; correctness net for worklist overflow)
__global__ __launch_bounds__(256)
void fixup2_kernel(const float* __restrict__ node, const float* __restrict__ edge,
                   const int* __restrict__ count, const int* __restrict__ worklist,
                   float* __restrict__ out, int start)
{
    __shared__ float sa[DD];
    __shared__ float zrow[EE];
    __shared__ float red[8];

    const int t    = threadIdx.x;
    const int lane = t & 63;
    const int wid  = t >> 6;
    const int nwork = count[0];

    for (int w = start + blockIdx.x; w < nwork; w += gridDim.x) {
        const int row = worklist[w];
        const int s = row / NN;
        const float* a = node + (size_t)row * DD;
        const float* B = edge + (size_t)s * EE * DD;

        __syncthreads();
        if (t < DD / 4) ((float4*)sa)[t] = ((const float4*)a)[t];
        __syncthreads();

        float4 va0 = ((const float4*)sa)[lane];
        float4 va1 = ((const float4*)sa)[64 + lane];

        for (int c = wid; c < EE; c += 4) {
            const float* b = B + (size_t)c * DD;
            float4 b0 = *(const float4*)(b + lane * 4);
            float4 b1 = *(const float4*)(b + 256 + lane * 4);
            float acc;
            acc = va0.x * b0.x;
            acc = fmaf(va0.y, b0.y, acc);
            acc = fmaf(va0.z, b0.z, acc);
            acc = fmaf(va0.w, b0.w, acc);
            acc = fmaf(va1.x, b1.x, acc);
            acc = fmaf(va1.y, b1.y, acc);
            acc = fmaf(va1.z, b1.z, acc);
            acc = fmaf(va1.w, b1.w, acc);
#pragma unroll
            for (int off = 32; off >= 1; off >>= 1)
                acc += __shfl_xor(acc, off, 64);
            if (lane == 0) zrow[c] = fmaxf(ALPHA * acc, 0.f);
        }
        __syncthreads();

        float z[4], m = 0.f;
#pragma unroll
        for (int j = 0; j < 4; ++j) {
            z[j] = zrow[j * 256 + t];
            m = fmaxf(m, z[j]);
        }
#pragma unroll
        for (int off = 32; off >= 1; off >>= 1)
            m = fmaxf(m, __shfl_xor(m, off, 64));
        if (lane == 0) red[wid] = m;
        __syncthreads();
        m = fmaxf(fmaxf(red[0], red[1]), fmaxf(red[2], red[3]));

        float e[4], sum = 0.f;
#pragma unroll
        for (int j = 0; j < 4; ++j) { e[j] = expf(z[j] - m); sum += e[j]; }
#pragma unroll
        for (int off = 32; off >= 1; off >>= 1)
            sum += __shfl_xor(sum, off, 64);
        if (lane == 0) red[4 + wid] = sum;
        __syncthreads();
        sum = red[4] + red[5] + red[6] + red[7];

        const float thr = 0.5f * sum;
#pragma unroll
        for (int j = 0; j < 4; ++j)
            out[(size_t)row * EE + j * 256 + t] = (e[j] > thr) ? 1.f : 0.f;
        __syncthreads();
    }
}

// ---------------- fallback fp32 path (round-0, verified) ----------------
#define BM 128
#define BN 128
#define BK 16
#define TM 8
#define TN 8

__global__ __launch_bounds__(256, 2)
void gemm_relu_kernel(const float* __restrict__ node,
                      const float* __restrict__ edge,
                      float* __restrict__ out)
{
    const int s  = blockIdx.z;
    const int m0 = blockIdx.y * BM;
    const int n0 = blockIdx.x * BN;

    const float* A = node + (size_t)s * NN * DD;
    const float* B = edge + (size_t)s * EE * DD;
    float*       C = out  + (size_t)s * NN * EE;

    __shared__ float As[BK][BM + 4];
    __shared__ float Bs[BK][BN + 4];

    const int tid = threadIdx.x;
    const int tx  = tid % 16;
    const int ty  = tid / 16;
    const int lrow = tid / 4;
    const int lcol = (tid % 4) * 4;

    float acc[TM][TN];
#pragma unroll
    for (int i = 0; i < TM; ++i)
#pragma unroll
        for (int j = 0; j < TN; ++j) acc[i][j] = 0.f;

    for (int k0 = 0; k0 < DD; k0 += BK) {
#pragma unroll
        for (int p = 0; p < 2; ++p) {
            const int r = lrow + p * 64;
            float4 v = *(const float4*)(A + (size_t)(m0 + r) * DD + k0 + lcol);
            As[lcol + 0][r] = v.x; As[lcol + 1][r] = v.y;
            As[lcol + 2][r] = v.z; As[lcol + 3][r] = v.w;
            float4 w = *(const float4*)(B + (size_t)(n0 + r) * DD + k0 + lcol);
            Bs[lcol + 0][r] = w.x; Bs[lcol + 1][r] = w.y;
            Bs[lcol + 2][r] = w.z; Bs[lcol + 3][r] = w.w;
        }
        __syncthreads();
#pragma unroll
        for (int k = 0; k < BK; ++k) {
            float a[TM], b[TN];
            float4 a0 = *(const float4*)&As[k][ty * 8];
            float4 a1 = *(const float4*)&As[k][ty * 8 + 4];
            a[0]=a0.x; a[1]=a0.y; a[2]=a0.z; a[3]=a0.w;
            a[4]=a1.x; a[5]=a1.y; a[6]=a1.z; a[7]=a1.w;
            float4 b0 = *(const float4*)&Bs[k][tx * 8];
            float4 b1 = *(const float4*)&Bs[k][tx * 8 + 4];
            b[0]=b0.x; b[1]=b0.y; b[2]=b0.z; b[3]=b0.w;
            b[4]=b1.x; b[5]=b1.y; b[6]=b1.z; b[7]=b1.w;
#pragma unroll
            for (int i = 0; i < TM; ++i)
#pragma unroll
                for (int j = 0; j < TN; ++j)
                    acc[i][j] = fmaf(a[i], b[j], acc[i][j]);
        }
        __syncthreads();
    }
#pragma unroll
    for (int i = 0; i < TM; ++i) {
        const size_t row = (size_t)(m0 + ty * 8 + i);
        float4 o0, o1;
        o0.x = fmaxf(ALPHA * acc[i][0], 0.f);
        o0.y = fmaxf(ALPHA * acc[i][1], 0.f);
        o0.z = fmaxf(ALPHA * acc[i][2], 0.f);
        o0.w = fmaxf(ALPHA * acc[i][3], 0.f);
        o1.x = fmaxf(ALPHA * acc[i][4], 0.f);
        o1.y = fmaxf(ALPHA * acc[i][5], 0.f);
        o1.z = fmaxf(ALPHA * acc[i][6], 0.f);
        o1.w = fmaxf(ALPHA * acc[i][7], 0.f);
        *(float4*)(C + row * EE + n0 + tx * 8)     = o0;
        *(float4*)(C + row * EE + n0 + tx * 8 + 4) = o1;
    }
}

__global__ __launch_bounds__(256)
void softmax_threshold_kernel(float* __restrict__ out)
{
    const int wave = threadIdx.x >> 6;
    const int lane = threadIdx.x & 63;
    const size_t row = (size_t)blockIdx.x * 4 + wave;
    float* p = out + row * EE;

    float z[16];
    float m = 0.f;
#pragma unroll
    for (int j = 0; j < 4; ++j) {
        float4 v = *(const float4*)(p + j * 256 + lane * 4);
        z[j*4+0] = v.x; z[j*4+1] = v.y; z[j*4+2] = v.z; z[j*4+3] = v.w;
        m = fmaxf(m, fmaxf(fmaxf(v.x, v.y), fmaxf(v.z, v.w)));
    }
#pragma unroll
    for (int off = 32; off >= 1; off >>= 1)
        m = fmaxf(m, __shfl_xor(m, off, 64));
    float e[16], sum = 0.f;
#pragma unroll
    for (int j = 0; j < 16; ++j) { e[j] = expf(z[j] - m); sum += e[j]; }
#pragma unroll
    for (int off = 32; off >= 1; off >>= 1)
        sum += __shfl_xor(sum, off, 64);
    const float thr = 0.5f * sum;
#pragma unroll
    for (int j = 0; j < 4; ++j) {
        float4 o;
        o.x = (e[j*4+0] > thr) ? 1.f : 0.f;
        o.y = (e[j*4+1] > thr) ? 1.f : 0.f;
        o.z = (e[j*4+2] > thr) ? 1.f : 0.f;
        o.w = (e[j*4+3] > thr) ? 1.f : 0.f;
        *(float4*)(p + j * 256 + lane * 4) = o;
    }
}

// ---------------- launch ----------------
extern "C" void kernel_launch(void* const* d_in, const int* in_sizes, int n_in,
                              void* d_out, int out_size, void* d_ws, size_t ws_size,
                              hipStream_t stream) {
    const float* node = (const float*)d_in[1];  // [S, N, D]
    const float* edge = (const float*)d_in[2];  // [S, E, D]
    float* out = (float*)d_out;                 // [S, N, E]

    const size_t SAe = (size_t)SS * NN * DD;    // node elems
    const size_t SBe = (size_t)SS * EE * DD;    // edge elems
    const size_t SZe = (size_t)SS * NN * EE;    // sim elems
    const size_t split_bytes = (2 * SAe + 2 * SBe) * 2;
    const size_t wl_bytes    = (size_t)(SS * NN + 1) * 4;
    const size_t base_need   = split_bytes + wl_bytes;

    if (ws_size >= base_need) {
        unsigned short* Ah = (unsigned short*)d_ws;
        unsigned short* Al = Ah + SAe;
        unsigned short* Bh = Al + SAe;
        unsigned short* Bl = Bh + SBe;
        int* count    = (int*)(Bl + SBe);
        int* worklist = count + 1;

        // optional u16-z buffer after the base region (256B aligned)
        const size_t z16_off = (base_need + 255) & ~(size_t)255;
        const size_t z16_end = z16_off + SZe * 2;

        // z-scratch for the parallel fixup: after z16 (u16 path) or after base
        unsigned short* z16 = nullptr;
        size_t zoff;
        if (ws_size >= z16_end + (size_t)64 * EE * 4) {   // need z16 + >=64-row zbuf
            z16  = (unsigned short*)((char*)d_ws + z16_off);
            zoff = (z16_end + 255) & ~(size_t)255;
        } else {
            zoff = z16_off;
        }
        int zcap = 0;
        if (ws_size > zoff) {
            size_t zc = (ws_size - zoff) / ((size_t)EE * 4);
            zcap = (int)(zc > 4096 ? 4096 : zc);
        }
        float* zbuf = (float*)((char*)d_ws + zoff);

        const int n4 = (int)((SAe + SBe) / 4);
        split_both_kernel<<<(n4 + 255) / 256, 256, 0, stream>>>(node, edge, Ah, Al, Bh, Bl, count);

        dim3 g1(NN / 128, EE / 128, SS);   // (64, 8, 3): m-fastest, A-panel on one XCD
        gemm_mfma_kernel<<<g1, 256, 0, stream>>>(Ah, Al, Bh, Bl, out, z16);

        if (z16 != nullptr) {
            softmax_threshold_flag16_kernel<<<(SS * NN) / 4, 256, 0, stream>>>(z16, out, count, worklist);
        } else {
            softmax_threshold_flag_kernel<<<(SS * NN) / 4, 256, 0, stream>>>(out, count, worklist);
        }

        if (zcap > 0) {
            fixup_z_kernel<<<1024, 256, 0, stream>>>(node, edge, count, worklist, zbuf, zcap);
            fixup_finish_kernel<<<64, 256, 0, stream>>>(zbuf, count, worklist, out, zcap);
        }
        // rows beyond zcap (never in practice): slow in-block path
        fixup2_kernel<<<128, 256, 0, stream>>>(node, edge, count, worklist, out, zcap);
    } else {
        dim3 g1(EE / BN, NN / BM, SS);
        gemm_relu_kernel<<<g1, 256, 0, stream>>>(node, edge, out);
        softmax_threshold_kernel<<<(SS * NN) / 4, 256, 0, stream>>>(out);
    }
}